// Round 1
// baseline (8760.303 us; speedup 1.0000x reference)
//
#include <hip/hip_runtime.h>
#include <math.h>

#define NNODES 10000
#define NEDGES 160000
#define EN_TOT (NNODES + NEDGES)  // 170000

// ---------- helpers ----------
static __device__ __forceinline__ unsigned enc_f(float f) {
    unsigned b = __float_as_uint(f);
    return (b & 0x80000000u) ? ~b : (b | 0x80000000u);  // order-preserving float->uint
}
static __device__ __forceinline__ float dec_f(unsigned u) {
    unsigned b = (u & 0x80000000u) ? (u & 0x7FFFFFFFu) : ~u;
    return __uint_as_float(b);
}

// ---------- generic fp32 GEMM: C = act(A[M,K] @ W[K,N] + bias) ----------
// 64x64 tile, BK=16, 256 threads, 4x4 micro-tile. N must be multiple of 64, K of 16.
__global__ __launch_bounds__(256) void gemm64(
    const float* __restrict__ A, const float* __restrict__ B,
    const float* __restrict__ bias, float* __restrict__ C,
    int M, int K, int Nn, int act) {
    __shared__ float As[16][68];
    __shared__ float Bs[16][68];
    int tid = threadIdx.x;
    int tx = tid & 15, ty = tid >> 4;
    int row0 = blockIdx.y * 64, col0 = blockIdx.x * 64;
    float acc[4][4] = {};
    for (int k0 = 0; k0 < K; k0 += 16) {
        int r = tid >> 2, c4 = (tid & 3) << 2;
        float4 av = make_float4(0.f, 0.f, 0.f, 0.f);
        if (row0 + r < M) av = *(const float4*)&A[(size_t)(row0 + r) * K + k0 + c4];
        As[c4 + 0][r] = av.x; As[c4 + 1][r] = av.y; As[c4 + 2][r] = av.z; As[c4 + 3][r] = av.w;
        int kk = tid >> 4, n4 = (tid & 15) << 2;
        *(float4*)&Bs[kk][n4] = *(const float4*)&B[(size_t)(k0 + kk) * Nn + col0 + n4];
        __syncthreads();
#pragma unroll
        for (int k2 = 0; k2 < 16; k2++) {
            float4 a4 = *(float4*)&As[k2][ty * 4];
            float4 b4 = *(float4*)&Bs[k2][tx * 4];
            float aa[4] = {a4.x, a4.y, a4.z, a4.w};
            float bb[4] = {b4.x, b4.y, b4.z, b4.w};
#pragma unroll
            for (int i = 0; i < 4; i++)
#pragma unroll
                for (int j = 0; j < 4; j++) acc[i][j] += aa[i] * bb[j];
        }
        __syncthreads();
    }
#pragma unroll
    for (int i = 0; i < 4; i++) {
        int gm = row0 + ty * 4 + i;
        if (gm >= M) continue;
        float4 v;
        float* vp = &v.x;
#pragma unroll
        for (int j = 0; j < 4; j++) {
            float t = acc[i][j];
            if (bias) t += bias[col0 + tx * 4 + j];
            if (act) t = fmaxf(t, 0.f);
            vp[j] = t;
        }
        *(float4*)&C[(size_t)gm * Nn + col0 + tx * 4] = v;
    }
}

// ---------- GAT attention scores per node: als/ald [N,2] ----------
__global__ __launch_bounds__(128) void gat_scores(
    const float* __restrict__ h, const float* __restrict__ a_src,
    const float* __restrict__ a_dst, float* __restrict__ als, float* __restrict__ ald) {
    int n = blockIdx.x;
    int w = threadIdx.x >> 6;  // head
    int l = threadIdx.x & 63;
    const float* hp = h + (size_t)n * 1024 + w * 512 + l * 8;
    const float* asp = a_src + w * 512 + l * 8;
    const float* adp = a_dst + w * 512 + l * 8;
    float s = 0.f, d = 0.f;
#pragma unroll
    for (int i = 0; i < 8; i++) { float hv = hp[i]; s += hv * asp[i]; d += hv * adp[i]; }
#pragma unroll
    for (int off = 32; off; off >>= 1) { s += __shfl_down(s, off); d += __shfl_down(d, off); }
    if (l == 0) { als[n * 2 + w] = s; ald[n * 2 + w] = d; }
}

// ---------- CSR build ----------
__global__ void k_count(const int* __restrict__ ei, int* __restrict__ cnt) {
    int e = blockIdx.x * blockDim.x + threadIdx.x;
    if (e >= EN_TOT) return;
    int d = (e < NEDGES) ? ei[NEDGES + e] : (e - NEDGES);
    atomicAdd(&cnt[d], 1);
}

__global__ __launch_bounds__(256) void k_scan(
    const int* __restrict__ cnt, int* __restrict__ rowstart,
    int* __restrict__ cursor, float* __restrict__ dinv) {
    __shared__ int buf[256];
    __shared__ int carry;
    int t = threadIdx.x;
    if (t == 0) carry = 0;
    __syncthreads();
    for (int base = 0; base < NNODES; base += 256) {
        int i = base + t;
        int v = (i < NNODES) ? cnt[i] : 0;
        buf[t] = v;
        __syncthreads();
        for (int off = 1; off < 256; off <<= 1) {
            int x = (t >= off) ? buf[t - off] : 0;
            __syncthreads();
            buf[t] += x;
            __syncthreads();
        }
        int incl = buf[t];
        int cbase = carry;
        if (i < NNODES) {
            int rs = cbase + incl - v;
            rowstart[i] = rs;
            cursor[i] = rs;
            dinv[i] = (v > 0) ? rsqrtf((float)v) : 0.f;
        }
        __syncthreads();
        if (t == 255) carry = cbase + incl;
        __syncthreads();
    }
    if (t == 0) rowstart[NNODES] = carry;
}

__global__ void k_fill(const int* __restrict__ ei, int* __restrict__ cursor,
                       int* __restrict__ csr_src, int* __restrict__ csr_eid) {
    int e = blockIdx.x * blockDim.x + threadIdx.x;
    if (e >= EN_TOT) return;
    int s, d;
    if (e < NEDGES) { s = ei[e]; d = ei[NEDGES + e]; } else { s = e - NEDGES; d = s; }
    int pos = atomicAdd(&cursor[d], 1);
    csr_src[pos] = s;
    csr_eid[pos] = e;
}

// ---------- GAT softmax over incoming edges ----------
__global__ void k_init_gat(unsigned* __restrict__ emax, float* __restrict__ esum) {
    int i = blockIdx.x * blockDim.x + threadIdx.x;
    if (i < NNODES * 2) { emax[i] = 0x007FFFFFu; /* enc(-inf) */ esum[i] = 0.f; }
}

__global__ void k_edge_score(const int* __restrict__ ei, const float* __restrict__ als,
                             const float* __restrict__ ald, float* __restrict__ score,
                             unsigned* __restrict__ emax) {
    int e = blockIdx.x * blockDim.x + threadIdx.x;
    if (e >= EN_TOT) return;
    int s, d;
    if (e < NEDGES) { s = ei[e]; d = ei[NEDGES + e]; } else { s = e - NEDGES; d = s; }
#pragma unroll
    for (int h = 0; h < 2; h++) {
        float v = als[s * 2 + h] + ald[d * 2 + h];
        v = (v > 0.f) ? v : 0.2f * v;  // leaky_relu 0.2
        score[e * 2 + h] = v;
        atomicMax(&emax[d * 2 + h], enc_f(v));
    }
}

__global__ void k_edge_exp(const int* __restrict__ ei, float* __restrict__ score,
                           const unsigned* __restrict__ emax, float* __restrict__ esum) {
    int e = blockIdx.x * blockDim.x + threadIdx.x;
    if (e >= EN_TOT) return;
    int d = (e < NEDGES) ? ei[NEDGES + e] : (e - NEDGES);
#pragma unroll
    for (int h = 0; h < 2; h++) {
        float m = dec_f(emax[d * 2 + h]);
        float x = expf(score[e * 2 + h] - m);
        score[e * 2 + h] = x;
        atomicAdd(&esum[d * 2 + h], x);
    }
}

// ---------- GAT aggregation (gather over CSR): out[n,1024] ----------
__global__ __launch_bounds__(256) void gat_aggregate(
    const float* __restrict__ hfeat, const float* __restrict__ ex,
    const float* __restrict__ esum, const int* __restrict__ rowstart,
    const int* __restrict__ csr_src, const int* __restrict__ csr_eid,
    const float* __restrict__ bias, float* __restrict__ out, int act) {
    int n = blockIdx.x;
    int t = threadIdx.x;
    int c0 = t * 4;
    int head = c0 >> 9;
    float inv = 1.f / (esum[n * 2 + head] + 1e-16f);
    int beg = rowstart[n], end = rowstart[n + 1];
    float4 acc = make_float4(0.f, 0.f, 0.f, 0.f);
    for (int p = beg; p < end; p++) {
        int s = csr_src[p];
        int eid = csr_eid[p];
        float alpha = ex[eid * 2 + head] * inv;
        float4 hv = *(const float4*)&hfeat[(size_t)s * 1024 + c0];
        acc.x += alpha * hv.x; acc.y += alpha * hv.y;
        acc.z += alpha * hv.z; acc.w += alpha * hv.w;
    }
    float4 bv = *(const float4*)&bias[c0];
    acc.x += bv.x; acc.y += bv.y; acc.z += bv.z; acc.w += bv.w;
    if (act) {
        acc.x = fmaxf(acc.x, 0.f); acc.y = fmaxf(acc.y, 0.f);
        acc.z = fmaxf(acc.z, 0.f); acc.w = fmaxf(acc.w, 0.f);
    }
    *(float4*)&out[(size_t)n * 1024 + c0] = acc;
}

// ---------- GCN aggregation (gather over CSR): out[n,512] ----------
__global__ __launch_bounds__(128) void gcn_aggregate(
    const float* __restrict__ hfeat, const float* __restrict__ dinv,
    const int* __restrict__ rowstart, const int* __restrict__ csr_src,
    const float* __restrict__ bias, float* __restrict__ out, int act) {
    int n = blockIdx.x;
    int t = threadIdx.x;
    int c0 = t * 4;
    float dn = dinv[n];
    int beg = rowstart[n], end = rowstart[n + 1];
    float4 acc = make_float4(0.f, 0.f, 0.f, 0.f);
    for (int p = beg; p < end; p++) {
        int s = csr_src[p];
        float w = dinv[s] * dn;
        float4 hv = *(const float4*)&hfeat[(size_t)s * 512 + c0];
        acc.x += w * hv.x; acc.y += w * hv.y; acc.z += w * hv.z; acc.w += w * hv.w;
    }
    float4 bv = *(const float4*)&bias[c0];
    acc.x += bv.x; acc.y += bv.y; acc.z += bv.z; acc.w += bv.w;
    if (act) {
        acc.x = fmaxf(acc.x, 0.f); acc.y = fmaxf(acc.y, 0.f);
        acc.z = fmaxf(acc.z, 0.f); acc.w = fmaxf(acc.w, 0.f);
    }
    *(float4*)&out[(size_t)n * 512 + c0] = acc;
}

// ---------- pdist via difference form (no cancellation, exact-0 diagonal) ----------
// 128x128 tile, BK=16, 256 threads, 8x8 micro-tile (split 4+4).
__global__ __launch_bounds__(256) void k_pdist(const float* __restrict__ X,
                                               float* __restrict__ out) {
    __shared__ float As[16][132];
    __shared__ float Bs[16][132];
    int tid = threadIdx.x;
    int tx = tid & 15, ty = tid >> 4;
    int row0 = blockIdx.y * 128, col0 = blockIdx.x * 128;
    float acc[8][8] = {};
    for (int k0 = 0; k0 < 1024; k0 += 16) {
#pragma unroll
        for (int s = 0; s < 2; s++) {
            int idx = tid + s * 256;
            int r = idx >> 2, c4 = (idx & 3) << 2;
            float4 av = make_float4(0.f, 0.f, 0.f, 0.f);
            int gr = row0 + r;
            if (gr < NNODES) av = *(const float4*)&X[(size_t)gr * 1024 + k0 + c4];
            As[c4 + 0][r] = av.x; As[c4 + 1][r] = av.y; As[c4 + 2][r] = av.z; As[c4 + 3][r] = av.w;
            float4 bv = make_float4(0.f, 0.f, 0.f, 0.f);
            int gc = col0 + r;
            if (gc < NNODES) bv = *(const float4*)&X[(size_t)gc * 1024 + k0 + c4];
            Bs[c4 + 0][r] = bv.x; Bs[c4 + 1][r] = bv.y; Bs[c4 + 2][r] = bv.z; Bs[c4 + 3][r] = bv.w;
        }
        __syncthreads();
#pragma unroll
        for (int kk = 0; kk < 16; kk++) {
            float a[8], b[8];
            *(float4*)&a[0] = *(float4*)&As[kk][ty * 4];
            *(float4*)&a[4] = *(float4*)&As[kk][64 + ty * 4];
            *(float4*)&b[0] = *(float4*)&Bs[kk][tx * 4];
            *(float4*)&b[4] = *(float4*)&Bs[kk][64 + tx * 4];
#pragma unroll
            for (int i = 0; i < 8; i++)
#pragma unroll
                for (int j = 0; j < 8; j++) {
                    float t = a[i] - b[j];
                    acc[i][j] += t * t;
                }
        }
        __syncthreads();
    }
#pragma unroll
    for (int i = 0; i < 8; i++) {
        int gi = row0 + (i < 4 ? (ty * 4 + i) : (64 + ty * 4 + i - 4));
        if (gi >= NNODES) continue;
#pragma unroll
        for (int jb = 0; jb < 2; jb++) {
            int gj = col0 + jb * 64 + tx * 4;
            if (gj >= NNODES) continue;  // N%4==0 so all-or-nothing per float4
            float4 v;
            v.x = sqrtf(acc[i][jb * 4 + 0]);
            v.y = sqrtf(acc[i][jb * 4 + 1]);
            v.z = sqrtf(acc[i][jb * 4 + 2]);
            v.w = sqrtf(acc[i][jb * 4 + 3]);
            *(float4*)&out[(size_t)gi * NNODES + gj] = v;
        }
    }
}

// ---------- launch ----------
extern "C" void kernel_launch(void* const* d_in, const int* in_sizes, int n_in,
                              void* d_out, int out_size, void* d_ws, size_t ws_size,
                              hipStream_t stream) {
    const float* x            = (const float*)d_in[0];
    const int*   ei           = (const int*)d_in[1];
    const float* enc_gat_W    = (const float*)d_in[2];
    const float* enc_gat_asrc = (const float*)d_in[3];
    const float* enc_gat_adst = (const float*)d_in[4];
    const float* enc_gat_b    = (const float*)d_in[5];
    const float* enc_gcn_W    = (const float*)d_in[6];
    const float* enc_gcn_b    = (const float*)d_in[7];
    const float* densea_W     = (const float*)d_in[8];
    const float* densea_b     = (const float*)d_in[9];
    const float* latent_W     = (const float*)d_in[10];
    const float* latent_b     = (const float*)d_in[11];
    const float* dec1_W       = (const float*)d_in[12];
    const float* dec1_b       = (const float*)d_in[13];
    const float* dec2_W       = (const float*)d_in[14];
    const float* dec2_b       = (const float*)d_in[15];
    const float* dec_gcn_W    = (const float*)d_in[16];
    const float* dec_gcn_b    = (const float*)d_in[17];
    const float* dec_gat_W    = (const float*)d_in[18];
    const float* dec_gat_asrc = (const float*)d_in[19];
    const float* dec_gat_adst = (const float*)d_in[20];
    const float* dec_gat_b    = (const float*)d_in[21];

    float* out = (float*)d_out;

    // ws layout (≈44.2 MB): dfeat must survive pdist, so it lives here.
    float*    dfeat    = (float*)d_ws;           // N*1024 = 10,240,000
    float*    score    = dfeat + 10240000;       // EN*2  =    340,000
    float*    esum     = score + 340000;         // 20,000
    unsigned* emax     = (unsigned*)(esum + 20000);  // 20,000
    float*    als      = (float*)(emax + 20000); // 20,000
    float*    ald      = als + 20000;            // 20,000
    int*      cnt      = (int*)(ald + 20000);    // 10,000
    int*      cursor   = cnt + 10000;            // 10,000
    int*      rowstart = cursor + 10000;         // 10,001
    float*    dinv     = (float*)(rowstart + 10001); // 10,000
    int*      csr_src  = (int*)(dinv + 10000);   // 170,000
    int*      csr_eid  = csr_src + 170000;       // 170,000

    // big intermediates live in d_out (overwritten by pdist at the end)
    float* bufA = out;             // N*1024
    float* bufB = out + 10500000;  // N*1024
    float* bufC = out + 21000000;  // N*512
    float* bufD = out + 26500000;  // N*512
    float* h128 = out + 32000000;  // N*128
    float* z64  = out + 33500000;  // N*64
    float* d128 = out + 34500000;  // N*128

    const int NT = 256;
    dim3 eb((EN_TOT + NT - 1) / NT);

    // graph structures (recomputed each call; ws is re-poisoned)
    hipMemsetAsync(cnt, 0, NNODES * sizeof(int), stream);
    k_count<<<eb, NT, 0, stream>>>(ei, cnt);
    k_scan<<<1, 256, 0, stream>>>(cnt, rowstart, cursor, dinv);
    k_fill<<<eb, NT, 0, stream>>>(ei, cursor, csr_src, csr_eid);

    auto gemm = [&](const float* A, const float* W, const float* bias, float* Cc,
                    int M, int K, int Nn, int act) {
        dim3 g(Nn / 64, (M + 63) / 64);
        gemm64<<<g, 256, 0, stream>>>(A, W, bias, Cc, M, K, Nn, act);
    };

    // ----- encoder GAT -----
    gemm(x, enc_gat_W, nullptr, bufA, NNODES, 512, 1024, 0);
    gat_scores<<<NNODES, 128, 0, stream>>>(bufA, enc_gat_asrc, enc_gat_adst, als, ald);
    k_init_gat<<<(2 * NNODES + 255) / 256, 256, 0, stream>>>(emax, esum);
    k_edge_score<<<eb, NT, 0, stream>>>(ei, als, ald, score, emax);
    k_edge_exp<<<eb, NT, 0, stream>>>(ei, score, emax, esum);
    gat_aggregate<<<NNODES, 256, 0, stream>>>(bufA, score, esum, rowstart, csr_src,
                                              csr_eid, enc_gat_b, bufB, 1);

    // ----- encoder GCN -----
    gemm(bufB, enc_gcn_W, nullptr, bufC, NNODES, 1024, 512, 0);
    gcn_aggregate<<<NNODES, 128, 0, stream>>>(bufC, dinv, rowstart, csr_src,
                                              enc_gcn_b, bufD, 1);

    // ----- dense encoder / decoder -----
    gemm(bufD, densea_W, densea_b, h128, NNODES, 512, 128, 1);
    gemm(h128, latent_W, latent_b, z64, NNODES, 128, 64, 0);
    gemm(z64, dec1_W, dec1_b, d128, NNODES, 64, 128, 1);
    gemm(d128, dec2_W, dec2_b, bufC, NNODES, 128, 512, 1);

    // ----- decoder GCN -----
    gemm(bufC, dec_gcn_W, nullptr, bufD, NNODES, 512, 512, 0);
    gcn_aggregate<<<NNODES, 128, 0, stream>>>(bufD, dinv, rowstart, csr_src,
                                              dec_gcn_b, bufC, 1);

    // ----- decoder GAT (no relu) -----
    gemm(bufC, dec_gat_W, nullptr, bufA, NNODES, 512, 1024, 0);
    gat_scores<<<NNODES, 128, 0, stream>>>(bufA, dec_gat_asrc, dec_gat_adst, als, ald);
    k_init_gat<<<(2 * NNODES + 255) / 256, 256, 0, stream>>>(emax, esum);
    k_edge_score<<<eb, NT, 0, stream>>>(ei, als, ald, score, emax);
    k_edge_exp<<<eb, NT, 0, stream>>>(ei, score, emax, esum);
    gat_aggregate<<<NNODES, 256, 0, stream>>>(bufA, score, esum, rowstart, csr_src,
                                              csr_eid, dec_gat_b, dfeat, 0);

    // ----- pairwise distances -----
    dim3 pg((NNODES + 127) / 128, (NNODES + 127) / 128);
    k_pdist<<<pg, 256, 0, stream>>>(dfeat, out);
}

// Round 2
// 3162.448 us; speedup vs baseline: 2.7701x; 2.7701x over previous
//
#include <hip/hip_runtime.h>
#include <math.h>

#define NNODES 10000
#define NEDGES 160000
#define EN_TOT (NNODES + NEDGES)  // 170000

typedef __attribute__((ext_vector_type(8))) short bf16x8;
typedef __attribute__((ext_vector_type(4))) float f32x4;
typedef __attribute__((address_space(1))) const void g_void;
typedef __attribute__((address_space(3))) void l_void;

// ---------- helpers ----------
static __device__ __forceinline__ unsigned enc_f(float f) {
    unsigned b = __float_as_uint(f);
    return (b & 0x80000000u) ? ~b : (b | 0x80000000u);  // order-preserving float->uint
}
static __device__ __forceinline__ float dec_f(unsigned u) {
    unsigned b = (u & 0x80000000u) ? (u & 0x7FFFFFFFu) : ~u;
    return __uint_as_float(b);
}
static __device__ __forceinline__ unsigned short f2bf(float f) {
    unsigned u = __float_as_uint(f);
    return (unsigned short)((u + 0x7FFFu + ((u >> 16) & 1u)) >> 16);  // RNE
}

// ---------- generic fp32 GEMM: C = act(A[M,K] @ W[K,N] + bias) ----------
__global__ __launch_bounds__(256) void gemm64(
    const float* __restrict__ A, const float* __restrict__ B,
    const float* __restrict__ bias, float* __restrict__ C,
    int M, int K, int Nn, int act) {
    __shared__ float As[16][68];
    __shared__ float Bs[16][68];
    int tid = threadIdx.x;
    int tx = tid & 15, ty = tid >> 4;
    int row0 = blockIdx.y * 64, col0 = blockIdx.x * 64;
    float acc[4][4] = {};
    for (int k0 = 0; k0 < K; k0 += 16) {
        int r = tid >> 2, c4 = (tid & 3) << 2;
        float4 av = make_float4(0.f, 0.f, 0.f, 0.f);
        if (row0 + r < M) av = *(const float4*)&A[(size_t)(row0 + r) * K + k0 + c4];
        As[c4 + 0][r] = av.x; As[c4 + 1][r] = av.y; As[c4 + 2][r] = av.z; As[c4 + 3][r] = av.w;
        int kk = tid >> 4, n4 = (tid & 15) << 2;
        *(float4*)&Bs[kk][n4] = *(const float4*)&B[(size_t)(k0 + kk) * Nn + col0 + n4];
        __syncthreads();
#pragma unroll
        for (int k2 = 0; k2 < 16; k2++) {
            float4 a4 = *(float4*)&As[k2][ty * 4];
            float4 b4 = *(float4*)&Bs[k2][tx * 4];
            float aa[4] = {a4.x, a4.y, a4.z, a4.w};
            float bb[4] = {b4.x, b4.y, b4.z, b4.w};
#pragma unroll
            for (int i = 0; i < 4; i++)
#pragma unroll
                for (int j = 0; j < 4; j++) acc[i][j] += aa[i] * bb[j];
        }
        __syncthreads();
    }
#pragma unroll
    for (int i = 0; i < 4; i++) {
        int gm = row0 + ty * 4 + i;
        if (gm >= M) continue;
        float4 v;
        float* vp = &v.x;
#pragma unroll
        for (int j = 0; j < 4; j++) {
            float t = acc[i][j];
            if (bias) t += bias[col0 + tx * 4 + j];
            if (act) t = fmaxf(t, 0.f);
            vp[j] = t;
        }
        *(float4*)&C[(size_t)gm * Nn + col0 + tx * 4] = v;
    }
}

// ---------- GAT attention scores per node: als/ald [N,2] ----------
__global__ __launch_bounds__(128) void gat_scores(
    const float* __restrict__ h, const float* __restrict__ a_src,
    const float* __restrict__ a_dst, float* __restrict__ als, float* __restrict__ ald) {
    int n = blockIdx.x;
    int w = threadIdx.x >> 6;  // head
    int l = threadIdx.x & 63;
    const float* hp = h + (size_t)n * 1024 + w * 512 + l * 8;
    const float* asp = a_src + w * 512 + l * 8;
    const float* adp = a_dst + w * 512 + l * 8;
    float s = 0.f, d = 0.f;
#pragma unroll
    for (int i = 0; i < 8; i++) { float hv = hp[i]; s += hv * asp[i]; d += hv * adp[i]; }
#pragma unroll
    for (int off = 32; off; off >>= 1) { s += __shfl_down(s, off); d += __shfl_down(d, off); }
    if (l == 0) { als[n * 2 + w] = s; ald[n * 2 + w] = d; }
}

// ---------- CSR build ----------
__global__ void k_count(const int* __restrict__ ei, int* __restrict__ cnt) {
    int e = blockIdx.x * blockDim.x + threadIdx.x;
    if (e >= EN_TOT) return;
    int d = (e < NEDGES) ? ei[NEDGES + e] : (e - NEDGES);
    atomicAdd(&cnt[d], 1);
}

__global__ __launch_bounds__(256) void k_scan(
    const int* __restrict__ cnt, int* __restrict__ rowstart,
    int* __restrict__ cursor, float* __restrict__ dinv) {
    __shared__ int buf[256];
    __shared__ int carry;
    int t = threadIdx.x;
    if (t == 0) carry = 0;
    __syncthreads();
    for (int base = 0; base < NNODES; base += 256) {
        int i = base + t;
        int v = (i < NNODES) ? cnt[i] : 0;
        buf[t] = v;
        __syncthreads();
        for (int off = 1; off < 256; off <<= 1) {
            int x = (t >= off) ? buf[t - off] : 0;
            __syncthreads();
            buf[t] += x;
            __syncthreads();
        }
        int incl = buf[t];
        int cbase = carry;
        if (i < NNODES) {
            int rs = cbase + incl - v;
            rowstart[i] = rs;
            cursor[i] = rs;
            dinv[i] = (v > 0) ? rsqrtf((float)v) : 0.f;
        }
        __syncthreads();
        if (t == 255) carry = cbase + incl;
        __syncthreads();
    }
    if (t == 0) rowstart[NNODES] = carry;
}

__global__ void k_fill(const int* __restrict__ ei, int* __restrict__ cursor,
                       int* __restrict__ csr_src, int* __restrict__ csr_eid) {
    int e = blockIdx.x * blockDim.x + threadIdx.x;
    if (e >= EN_TOT) return;
    int s, d;
    if (e < NEDGES) { s = ei[e]; d = ei[NEDGES + e]; } else { s = e - NEDGES; d = s; }
    int pos = atomicAdd(&cursor[d], 1);
    csr_src[pos] = s;
    csr_eid[pos] = e;
}

// ---------- GAT softmax over incoming edges ----------
__global__ void k_init_gat(unsigned* __restrict__ emax, float* __restrict__ esum) {
    int i = blockIdx.x * blockDim.x + threadIdx.x;
    if (i < NNODES * 2) { emax[i] = 0x007FFFFFu; esum[i] = 0.f; }
}

__global__ void k_edge_score(const int* __restrict__ ei, const float* __restrict__ als,
                             const float* __restrict__ ald, float* __restrict__ score,
                             unsigned* __restrict__ emax) {
    int e = blockIdx.x * blockDim.x + threadIdx.x;
    if (e >= EN_TOT) return;
    int s, d;
    if (e < NEDGES) { s = ei[e]; d = ei[NEDGES + e]; } else { s = e - NEDGES; d = s; }
#pragma unroll
    for (int h = 0; h < 2; h++) {
        float v = als[s * 2 + h] + ald[d * 2 + h];
        v = (v > 0.f) ? v : 0.2f * v;  // leaky_relu 0.2
        score[e * 2 + h] = v;
        atomicMax(&emax[d * 2 + h], enc_f(v));
    }
}

__global__ void k_edge_exp(const int* __restrict__ ei, float* __restrict__ score,
                           const unsigned* __restrict__ emax, float* __restrict__ esum) {
    int e = blockIdx.x * blockDim.x + threadIdx.x;
    if (e >= EN_TOT) return;
    int d = (e < NEDGES) ? ei[NEDGES + e] : (e - NEDGES);
#pragma unroll
    for (int h = 0; h < 2; h++) {
        float m = dec_f(emax[d * 2 + h]);
        float x = expf(score[e * 2 + h] - m);
        score[e * 2 + h] = x;
        atomicAdd(&esum[d * 2 + h], x);
    }
}

// ---------- GAT aggregation (gather over CSR): out[n,1024] ----------
__global__ __launch_bounds__(256) void gat_aggregate(
    const float* __restrict__ hfeat, const float* __restrict__ ex,
    const float* __restrict__ esum, const int* __restrict__ rowstart,
    const int* __restrict__ csr_src, const int* __restrict__ csr_eid,
    const float* __restrict__ bias, float* __restrict__ out, int act) {
    int n = blockIdx.x;
    int t = threadIdx.x;
    int c0 = t * 4;
    int head = c0 >> 9;
    float inv = 1.f / (esum[n * 2 + head] + 1e-16f);
    int beg = rowstart[n], end = rowstart[n + 1];
    float4 acc = make_float4(0.f, 0.f, 0.f, 0.f);
    for (int p = beg; p < end; p++) {
        int s = csr_src[p];
        int eid = csr_eid[p];
        float alpha = ex[eid * 2 + head] * inv;
        float4 hv = *(const float4*)&hfeat[(size_t)s * 1024 + c0];
        acc.x += alpha * hv.x; acc.y += alpha * hv.y;
        acc.z += alpha * hv.z; acc.w += alpha * hv.w;
    }
    float4 bv = *(const float4*)&bias[c0];
    acc.x += bv.x; acc.y += bv.y; acc.z += bv.z; acc.w += bv.w;
    if (act) {
        acc.x = fmaxf(acc.x, 0.f); acc.y = fmaxf(acc.y, 0.f);
        acc.z = fmaxf(acc.z, 0.f); acc.w = fmaxf(acc.w, 0.f);
    }
    *(float4*)&out[(size_t)n * 1024 + c0] = acc;
}

// ---------- GCN aggregation (gather over CSR): out[n,512] ----------
__global__ __launch_bounds__(128) void gcn_aggregate(
    const float* __restrict__ hfeat, const float* __restrict__ dinv,
    const int* __restrict__ rowstart, const int* __restrict__ csr_src,
    const float* __restrict__ bias, float* __restrict__ out, int act) {
    int n = blockIdx.x;
    int t = threadIdx.x;
    int c0 = t * 4;
    float dn = dinv[n];
    int beg = rowstart[n], end = rowstart[n + 1];
    float4 acc = make_float4(0.f, 0.f, 0.f, 0.f);
    for (int p = beg; p < end; p++) {
        int s = csr_src[p];
        float w = dinv[s] * dn;
        float4 hv = *(const float4*)&hfeat[(size_t)s * 512 + c0];
        acc.x += w * hv.x; acc.y += w * hv.y; acc.z += w * hv.z; acc.w += w * hv.w;
    }
    float4 bv = *(const float4*)&bias[c0];
    acc.x += bv.x; acc.y += bv.y; acc.z += bv.z; acc.w += bv.w;
    if (act) {
        acc.x = fmaxf(acc.x, 0.f); acc.y = fmaxf(acc.y, 0.f);
        acc.z = fmaxf(acc.z, 0.f); acc.w = fmaxf(acc.w, 0.f);
    }
    *(float4*)&out[(size_t)n * 512 + c0] = acc;
}

// ---------- split fp32 -> (bf16 hi, bf16 lo) + squared norms ----------
__global__ __launch_bounds__(256) void k_split(
    const float* __restrict__ X, unsigned short* __restrict__ hi,
    unsigned short* __restrict__ lo, float* __restrict__ sqn) {
    __shared__ float wsum[4];
    int n = blockIdx.x;
    int t = threadIdx.x;
    float4 v = *(const float4*)&X[(size_t)n * 1024 + t * 4];
    float vv[4] = {v.x, v.y, v.z, v.w};
    ushort4 hv, lv;
    unsigned short* hp = &hv.x;
    unsigned short* lp = &lv.x;
    float s = 0.f;
#pragma unroll
    for (int i = 0; i < 4; i++) {
        float f = vv[i];
        s += f * f;
        unsigned short hb = f2bf(f);
        hp[i] = hb;
        float fh = __uint_as_float(((unsigned)hb) << 16);
        lp[i] = f2bf(f - fh);
    }
    *(ushort4*)&hi[(size_t)n * 1024 + t * 4] = hv;
    *(ushort4*)&lo[(size_t)n * 1024 + t * 4] = lv;
#pragma unroll
    for (int off = 32; off; off >>= 1) s += __shfl_down(s, off);
    if ((t & 63) == 0) wsum[t >> 6] = s;
    __syncthreads();
    if (t == 0) sqn[n] = wsum[0] + wsum[1] + wsum[2] + wsum[3];
}

// ---------- pdist via bf16-split MFMA Gram + norms ----------
// 128x128 tile, 4 waves (2x2), 16x16x32 bf16 MFMA, 3-term split (hh+hl+lh).
// LDS per matrix: k-chunk-major [kchunk][row][8 bf16] so global_load_lds's
// (uniform base + lane*16) constraint matches the frag-read layout.
__global__ __launch_bounds__(256) void k_gram_pdist(
    const unsigned short* __restrict__ Xhi, const unsigned short* __restrict__ Xlo,
    const float* __restrict__ sq, float* __restrict__ out) {
    __shared__ unsigned short lds[16384];  // 4 x 8KB
    const int tid = threadIdx.x;
    const int lane = tid & 63;
    const int w = tid >> 6;  // wave id == staged matrix id
    const int row0 = blockIdx.y * 128;
    const int col0 = blockIdx.x * 128;
    const int wr = w >> 1, wc = w & 1;

    // matrix 0: Xhi@row0, 1: Xlo@row0, 2: Xhi@col0, 3: Xlo@col0
    const unsigned short* mat = (w & 1) ? Xlo : Xhi;
    const int nbase = (w < 2) ? row0 : col0;

    f32x4 acc[4][4];
#pragma unroll
    for (int i = 0; i < 4; i++)
#pragma unroll
        for (int j = 0; j < 4; j++) acc[i][j] = (f32x4){0.f, 0.f, 0.f, 0.f};

    const int q = lane >> 4;       // frag k-chunk
    const int r16 = lane & 15;

    for (int k0 = 0; k0 < 1024; k0 += 32) {
        // stage: 8 x 1KB global_load_lds per wave (wave w fills matrix w)
#pragma unroll
        for (int s = 0; s < 8; s++) {
            int kchunk = s >> 1;
            int row = ((s & 1) << 6) + lane;
            int node = nbase + row;
            if (node > NNODES - 1) node = NNODES - 1;
            const unsigned short* gp = mat + (size_t)node * 1024 + k0 + kchunk * 8;
            unsigned short* lp = &lds[w * 4096 + s * 512];  // wave-uniform
            __builtin_amdgcn_global_load_lds((g_void*)gp, (l_void*)lp, 16, 0, 0);
        }
        __syncthreads();

        bf16x8 ah[4], al[4], bh[4], bl[4];
#pragma unroll
        for (int t = 0; t < 4; t++) {
            int aoff = q * 1024 + (wr * 64 + t * 16 + r16) * 8;
            ah[t] = *(const bf16x8*)&lds[aoff];
            al[t] = *(const bf16x8*)&lds[4096 + aoff];
            int boff = q * 1024 + (wc * 64 + t * 16 + r16) * 8;
            bh[t] = *(const bf16x8*)&lds[8192 + boff];
            bl[t] = *(const bf16x8*)&lds[12288 + boff];
        }
#pragma unroll
        for (int i = 0; i < 4; i++)
#pragma unroll
            for (int j = 0; j < 4; j++) {
                acc[i][j] = __builtin_amdgcn_mfma_f32_16x16x32_bf16(ah[i], bh[j], acc[i][j], 0, 0, 0);
                acc[i][j] = __builtin_amdgcn_mfma_f32_16x16x32_bf16(ah[i], bl[j], acc[i][j], 0, 0, 0);
                acc[i][j] = __builtin_amdgcn_mfma_f32_16x16x32_bf16(al[i], bh[j], acc[i][j], 0, 0, 0);
            }
        __syncthreads();
    }

    // epilogue: d = sqrt(max(sq_i + sq_j - 2G, 0)); diagonal forced to 0
    const int q4 = (lane >> 4) * 4;
#pragma unroll
    for (int j = 0; j < 4; j++) {
        int gj = col0 + wc * 64 + j * 16 + r16;
        bool jv = gj < NNODES;
        float sqj = jv ? sq[gj] : 0.f;
#pragma unroll
        for (int i = 0; i < 4; i++) {
            int gibase = row0 + wr * 64 + i * 16 + q4;
#pragma unroll
            for (int r = 0; r < 4; r++) {
                int gi = gibase + r;
                if (gi < NNODES && jv) {
                    float d2 = sq[gi] + sqj - 2.f * acc[i][j][r];
                    float d = (gi == gj) ? 0.f : sqrtf(fmaxf(d2, 0.f));
                    out[(size_t)gi * NNODES + gj] = d;
                }
            }
        }
    }
}

// ---------- launch ----------
extern "C" void kernel_launch(void* const* d_in, const int* in_sizes, int n_in,
                              void* d_out, int out_size, void* d_ws, size_t ws_size,
                              hipStream_t stream) {
    const float* x            = (const float*)d_in[0];
    const int*   ei           = (const int*)d_in[1];
    const float* enc_gat_W    = (const float*)d_in[2];
    const float* enc_gat_asrc = (const float*)d_in[3];
    const float* enc_gat_adst = (const float*)d_in[4];
    const float* enc_gat_b    = (const float*)d_in[5];
    const float* enc_gcn_W    = (const float*)d_in[6];
    const float* enc_gcn_b    = (const float*)d_in[7];
    const float* densea_W     = (const float*)d_in[8];
    const float* densea_b     = (const float*)d_in[9];
    const float* latent_W     = (const float*)d_in[10];
    const float* latent_b     = (const float*)d_in[11];
    const float* dec1_W       = (const float*)d_in[12];
    const float* dec1_b       = (const float*)d_in[13];
    const float* dec2_W       = (const float*)d_in[14];
    const float* dec2_b       = (const float*)d_in[15];
    const float* dec_gcn_W    = (const float*)d_in[16];
    const float* dec_gcn_b    = (const float*)d_in[17];
    const float* dec_gat_W    = (const float*)d_in[18];
    const float* dec_gat_asrc = (const float*)d_in[19];
    const float* dec_gat_adst = (const float*)d_in[20];
    const float* dec_gat_b    = (const float*)d_in[21];

    float* out = (float*)d_out;

    // ws layout (~24 MB): split matrices must survive pdist.
    unsigned short* Xhi = (unsigned short*)d_ws;   // 10,240,000 ushort
    unsigned short* Xlo = Xhi + 10240000;          // 10,240,000 ushort
    float*    sqn      = (float*)(Xlo + 10240000); // 10,000
    float*    score    = sqn + 10000;              // EN*2 = 340,000
    float*    esum     = score + 340000;           // 20,000
    unsigned* emax     = (unsigned*)(esum + 20000);
    float*    als      = (float*)(emax + 20000);
    float*    ald      = als + 20000;
    int*      cnt      = (int*)(ald + 20000);
    int*      cursor   = cnt + 10000;
    int*      rowstart = cursor + 10000;           // 10,001
    float*    dinv     = (float*)(rowstart + 10001);
    int*      csr_src  = (int*)(dinv + 10000);     // 170,000
    int*      csr_eid  = csr_src + 170000;         // 170,000

    // big intermediates live in d_out (overwritten by pdist at the end)
    float* bufA = out;             // N*1024
    float* bufB = out + 10500000;  // N*1024  (also decoder-GAT output / pre-split feat)
    float* bufC = out + 21000000;  // N*512
    float* bufD = out + 26500000;  // N*512
    float* h128 = out + 32000000;  // N*128
    float* z64  = out + 33500000;  // N*64
    float* d128 = out + 34500000;  // N*128

    const int NT = 256;
    dim3 eb((EN_TOT + NT - 1) / NT);

    hipMemsetAsync(cnt, 0, NNODES * sizeof(int), stream);
    k_count<<<eb, NT, 0, stream>>>(ei, cnt);
    k_scan<<<1, 256, 0, stream>>>(cnt, rowstart, cursor, dinv);
    k_fill<<<eb, NT, 0, stream>>>(ei, cursor, csr_src, csr_eid);

    auto gemm = [&](const float* A, const float* W, const float* bias, float* Cc,
                    int M, int K, int Nn, int act) {
        dim3 g(Nn / 64, (M + 63) / 64);
        gemm64<<<g, 256, 0, stream>>>(A, W, bias, Cc, M, K, Nn, act);
    };

    // ----- encoder GAT -----
    gemm(x, enc_gat_W, nullptr, bufA, NNODES, 512, 1024, 0);
    gat_scores<<<NNODES, 128, 0, stream>>>(bufA, enc_gat_asrc, enc_gat_adst, als, ald);
    k_init_gat<<<(2 * NNODES + 255) / 256, 256, 0, stream>>>(emax, esum);
    k_edge_score<<<eb, NT, 0, stream>>>(ei, als, ald, score, emax);
    k_edge_exp<<<eb, NT, 0, stream>>>(ei, score, emax, esum);
    gat_aggregate<<<NNODES, 256, 0, stream>>>(bufA, score, esum, rowstart, csr_src,
                                              csr_eid, enc_gat_b, bufB, 1);

    // ----- encoder GCN -----
    gemm(bufB, enc_gcn_W, nullptr, bufC, NNODES, 1024, 512, 0);
    gcn_aggregate<<<NNODES, 128, 0, stream>>>(bufC, dinv, rowstart, csr_src,
                                              enc_gcn_b, bufD, 1);

    // ----- dense encoder / decoder -----
    gemm(bufD, densea_W, densea_b, h128, NNODES, 512, 128, 1);
    gemm(h128, latent_W, latent_b, z64, NNODES, 128, 64, 0);
    gemm(z64, dec1_W, dec1_b, d128, NNODES, 64, 128, 1);
    gemm(d128, dec2_W, dec2_b, bufC, NNODES, 128, 512, 1);

    // ----- decoder GCN -----
    gemm(bufC, dec_gcn_W, nullptr, bufD, NNODES, 512, 512, 0);
    gcn_aggregate<<<NNODES, 128, 0, stream>>>(bufD, dinv, rowstart, csr_src,
                                              dec_gcn_b, bufC, 1);

    // ----- decoder GAT (no relu) -> bufB -----
    gemm(bufC, dec_gat_W, nullptr, bufA, NNODES, 512, 1024, 0);
    gat_scores<<<NNODES, 128, 0, stream>>>(bufA, dec_gat_asrc, dec_gat_adst, als, ald);
    k_init_gat<<<(2 * NNODES + 255) / 256, 256, 0, stream>>>(emax, esum);
    k_edge_score<<<eb, NT, 0, stream>>>(ei, als, ald, score, emax);
    k_edge_exp<<<eb, NT, 0, stream>>>(ei, score, emax, esum);
    gat_aggregate<<<NNODES, 256, 0, stream>>>(bufA, score, esum, rowstart, csr_src,
                                              csr_eid, dec_gat_b, bufB, 0);

    // ----- split + norms, then MFMA pdist -----
    k_split<<<NNODES, 256, 0, stream>>>(bufB, Xhi, Xlo, sqn);
    dim3 pg((NNODES + 127) / 128, (NNODES + 127) / 128);
    k_gram_pdist<<<pg, 256, 0, stream>>>(Xhi, Xlo, sqn, out);
}